// Round 2
// baseline (354.523 us; speedup 1.0000x reference)
//
#include <hip/hip_runtime.h>
#include <math.h>

// critic_attention, round 2: 4 waves cooperate on 64 items.
//   wave w ∈ {0..3}: layer0+tanh for agents {w*4 .. w*4+3} (agent 0 = self, wave 0),
//   online partial softmax per wave, barriered LDS merge, then wave w computes
//   output columns [w*32, w*32+32) of W2, W3, Wc.
// All weight accesses are wave-uniform (readfirstlane'd wq) -> s_load streams.
// Odd LDS strides (129/65/9) -> 2-way bank aliasing only (free).

#define SLOPE 0.01f
#define LOG2E 1.4426950408889634f

__device__ __forceinline__ float lrelu(float x) { return fmaxf(x, SLOPE * x); }

__device__ __forceinline__ float fast_tanh(float x) {
    float e = exp2f(x * (2.0f * LOG2E));
    return 1.0f - __fdividef(2.0f, e + 1.0f);
}

// h[c] = b0[c] + sum_f x[f] * W0[f][c]   (40 features: 32 obs + 8 act)
__device__ __forceinline__ void layer0(float h[64], const float* __restrict__ orow,
                                       const float* __restrict__ arow,
                                       const float* __restrict__ W0,
                                       const float* __restrict__ b0) {
#pragma unroll
    for (int c = 0; c < 64; ++c) h[c] = b0[c];
#pragma unroll
    for (int f4 = 0; f4 < 8; ++f4) {
        float4 xv = *reinterpret_cast<const float4*>(orow + f4 * 4);
        const float* w = W0 + f4 * 4 * 64;
#pragma unroll
        for (int c = 0; c < 64; ++c) {
            h[c] = fmaf(xv.x, w[c], h[c]);
            h[c] = fmaf(xv.y, w[c + 64], h[c]);
            h[c] = fmaf(xv.z, w[c + 128], h[c]);
            h[c] = fmaf(xv.w, w[c + 192], h[c]);
        }
    }
#pragma unroll
    for (int f4 = 0; f4 < 2; ++f4) {
        float4 xv = *reinterpret_cast<const float4*>(arow + f4 * 4);
        const float* w = W0 + (32 + f4 * 4) * 64;
#pragma unroll
        for (int c = 0; c < 64; ++c) {
            h[c] = fmaf(xv.x, w[c], h[c]);
            h[c] = fmaf(xv.y, w[c + 64], h[c]);
            h[c] = fmaf(xv.z, w[c + 128], h[c]);
            h[c] = fmaf(xv.w, w[c + 192], h[c]);
        }
    }
}

// in-place tanh of h, returns dot(tanh(h), W1o[0..63])
__device__ __forceinline__ float tanh_dot(float h[64], const float* __restrict__ W1o) {
    float d0 = 0.f, d1 = 0.f, d2 = 0.f, d3 = 0.f;
#pragma unroll
    for (int c = 0; c < 64; c += 4) {
        h[c + 0] = fast_tanh(h[c + 0]);
        h[c + 1] = fast_tanh(h[c + 1]);
        h[c + 2] = fast_tanh(h[c + 2]);
        h[c + 3] = fast_tanh(h[c + 3]);
        d0 = fmaf(h[c + 0], W1o[c + 0], d0);
        d1 = fmaf(h[c + 1], W1o[c + 1], d1);
        d2 = fmaf(h[c + 2], W1o[c + 2], d2);
        d3 = fmaf(h[c + 3], W1o[c + 3], d3);
    }
    return (d0 + d1) + (d2 + d3);
}

__global__ __launch_bounds__(256, 3) void critic_attention_kernel(
    const float* __restrict__ obs, const float* __restrict__ act,
    const float* __restrict__ W0, const float* __restrict__ b0,
    const float* __restrict__ W1, const float* __restrict__ b1v,
    const float* __restrict__ W2, const float* __restrict__ b2,
    const float* __restrict__ W3, const float* __restrict__ b3,
    const float* __restrict__ Wc, const float* __restrict__ bcv,
    float* __restrict__ out)
{
    __shared__ float xc[64 * 129];   // x_cat then x1 (stride 129: odd -> 2-way alias)
    __shared__ float pbuf[64 * 65];  // xsum partial staging
    __shared__ float sm[64 * 9];     // [0]=a_self, [1..4]=m_w, [5..8]=s_w (later Wc partials)

    const int t = threadIdx.x;
    const int il = t & 63;
    const int wq = __builtin_amdgcn_readfirstlane(t >> 6);

    const long item = (long)blockIdx.x * 64 + il;
    const float* orow = obs + item * 512;
    const float* arow = act + item * 128;

    float h[64], xsum[64];
    float m, s, d_first = 0.f;

    // ---------- pre-barrier: wave0 does agent 0 (self); waves 1-3 do their first agent ----------
    if (wq == 0) {
        layer0(h, orow, arow, W0, b0);
        float a0 = 0.f, a1 = 0.f, a2 = 0.f, a3 = 0.f;
#pragma unroll
        for (int c = 0; c < 64; c += 4) {
            float s0 = lrelu(h[c + 0]);
            float s1 = lrelu(h[c + 1]);
            float s2 = lrelu(h[c + 2]);
            float s3 = lrelu(h[c + 3]);
            xc[il * 129 + c + 0] = s0;
            xc[il * 129 + c + 1] = s1;
            xc[il * 129 + c + 2] = s2;
            xc[il * 129 + c + 3] = s3;
            a0 = fmaf(s0, W1[c + 0], a0);
            a1 = fmaf(s1, W1[c + 1], a1);
            a2 = fmaf(s2, W1[c + 2], a2);
            a3 = fmaf(s3, W1[c + 3], a3);
        }
        sm[il * 9] = b1v[0] + ((a0 + a1) + (a2 + a3));
    } else {
        const int n = wq * 4;
        layer0(h, orow + n * 32, arow + n * 8, W0, b0);
        d_first = tanh_dot(h, W1 + 64);
    }
    __syncthreads();

    const float a_self = sm[il * 9];

    if (wq == 0) {
        m = -INFINITY; s = 0.f;
#pragma unroll
        for (int c = 0; c < 64; ++c) xsum[c] = 0.f;
    } else {
        float l = lrelu(a_self + d_first);
        m = l; s = 1.f;
#pragma unroll
        for (int c = 0; c < 64; ++c) xsum[c] = h[c];
    }

    // ---------- remaining 3 agents per wave, online softmax ----------
    const int nbase = (wq == 0) ? 1 : wq * 4 + 1;
    for (int k = 0; k < 3; ++k) {
        const int n = nbase + k;
        layer0(h, orow + n * 32, arow + n * 8, W0, b0);
        float d = tanh_dot(h, W1 + 64);
        float l = lrelu(a_self + d);
        float mn = fmaxf(m, l);
        float f = exp2f((m - mn) * LOG2E);
        float e = exp2f((l - mn) * LOG2E);
        s = fmaf(s, f, e);
        m = mn;
#pragma unroll
        for (int c = 0; c < 64; ++c) xsum[c] = fmaf(xsum[c], f, e * h[c]);
    }

    // ---------- cross-wave softmax merge ----------
    sm[il * 9 + 1 + wq] = m;
    sm[il * 9 + 5 + wq] = s;
    __syncthreads();

    const float m0 = sm[il * 9 + 1], m1 = sm[il * 9 + 2];
    const float m2 = sm[il * 9 + 3], m3 = sm[il * 9 + 4];
    const float s0 = sm[il * 9 + 5], s1 = sm[il * 9 + 6];
    const float s2 = sm[il * 9 + 7], s3 = sm[il * 9 + 8];
    const float M = fmaxf(fmaxf(m0, m1), fmaxf(m2, m3));
    const float f0 = exp2f((m0 - M) * LOG2E);
    const float f1 = exp2f((m1 - M) * LOG2E);
    const float f2 = exp2f((m2 - M) * LOG2E);
    const float f3 = exp2f((m3 - M) * LOG2E);
    const float S = fmaf(s0, f0, fmaf(s1, f1, fmaf(s2, f2, s3 * f3)));
    const float fw = (wq == 0) ? f0 : (wq == 1) ? f1 : (wq == 2) ? f2 : f3;

    if (wq == 1) {
#pragma unroll
        for (int c = 0; c < 64; ++c) pbuf[il * 65 + c] = xsum[c] * fw;
    }
    __syncthreads();
    if (wq == 2) {
#pragma unroll
        for (int c = 0; c < 64; ++c) pbuf[il * 65 + c] += xsum[c] * fw;
    }
    __syncthreads();
    if (wq == 3) {
#pragma unroll
        for (int c = 0; c < 64; ++c) pbuf[il * 65 + c] += xsum[c] * fw;
    }
    __syncthreads();
    if (wq == 0) {
        const float inv = __fdividef(1.0f, S);
#pragma unroll
        for (int c = 0; c < 64; ++c)
            xc[il * 129 + 64 + c] = (fmaf(xsum[c], fw, pbuf[il * 65 + c])) * inv;
    }
    __syncthreads();

    // ---------- x1 = lrelu(x_cat @ W2 + b2): wave w does columns [w*32, w*32+32) ----------
    const int jb = wq * 32;
    float acc[32];
#pragma unroll
    for (int jj = 0; jj < 32; ++jj) acc[jj] = b2[jb + jj];
#pragma unroll 4
    for (int i = 0; i < 128; ++i) {
        float xv = xc[il * 129 + i];
        const float* wr = W2 + i * 128 + jb;
#pragma unroll
        for (int jj = 0; jj < 32; ++jj) acc[jj] = fmaf(xv, wr[jj], acc[jj]);
    }
    __syncthreads();   // everyone done reading x_cat
#pragma unroll
    for (int jj = 0; jj < 32; ++jj) xc[il * 129 + jb + jj] = lrelu(acc[jj]);
    __syncthreads();

    // ---------- x2 = lrelu(x1 @ W3 + b3), same column split ----------
#pragma unroll
    for (int jj = 0; jj < 32; ++jj) acc[jj] = b3[jb + jj];
#pragma unroll 4
    for (int i = 0; i < 128; ++i) {
        float xv = xc[il * 129 + i];
        const float* wr = W3 + i * 128 + jb;
#pragma unroll
        for (int jj = 0; jj < 32; ++jj) acc[jj] = fmaf(xv, wr[jj], acc[jj]);
    }

    // ---------- value = x2 @ Wc + bc: per-wave partial then merge ----------
    float v0 = 0.f, v1 = 0.f, v2 = 0.f, v3 = 0.f;
#pragma unroll
    for (int jj = 0; jj < 32; jj += 4) {
        v0 = fmaf(lrelu(acc[jj + 0]), Wc[jb + jj + 0], v0);
        v1 = fmaf(lrelu(acc[jj + 1]), Wc[jb + jj + 1], v1);
        v2 = fmaf(lrelu(acc[jj + 2]), Wc[jb + jj + 2], v2);
        v3 = fmaf(lrelu(acc[jj + 3]), Wc[jb + jj + 3], v3);
    }
    sm[il * 9 + 1 + wq] = ((v0 + v1) + (v2 + v3));   // sm free now: reuse for partials
    __syncthreads();
    if (wq == 0) {
        out[item] = bcv[0] + ((sm[il * 9 + 1] + sm[il * 9 + 2]) +
                              (sm[il * 9 + 3] + sm[il * 9 + 4]));
    }
}

extern "C" void kernel_launch(void* const* d_in, const int* in_sizes, int n_in,
                              void* d_out, int out_size, void* d_ws, size_t ws_size,
                              hipStream_t stream) {
    (void)in_sizes; (void)n_in; (void)d_ws; (void)ws_size; (void)out_size;
    const float* obs = (const float*)d_in[0];
    const float* act = (const float*)d_in[1];
    const float* W0  = (const float*)d_in[2];
    const float* b0  = (const float*)d_in[3];
    const float* W1  = (const float*)d_in[4];
    const float* b1  = (const float*)d_in[5];
    const float* W2  = (const float*)d_in[6];
    const float* b2  = (const float*)d_in[7];
    const float* W3  = (const float*)d_in[8];
    const float* b3  = (const float*)d_in[9];
    const float* Wc  = (const float*)d_in[10];
    const float* bc  = (const float*)d_in[11];

    critic_attention_kernel<<<dim3(65536 / 64), dim3(256), 0, stream>>>(
        obs, act, W0, b0, W1, b1, W2, b2, W3, b3, Wc, bc, (float*)d_out);
}